// Round 1
// baseline (1050.441 us; speedup 1.0000x reference)
//
#include <hip/hip_runtime.h>
#include <math.h>

#define MULT 32
#define NSPEC 10
#define NGRAPH 16
#define NODE_TILE 16
#define INV_SC 0.05590169943749474f   /* 1/sqrt(32*10) */
#define INV32S 0.17677669529663687f   /* 1/sqrt(32) */

// ---------------------------------------------------------------------------
// small utility kernels
// ---------------------------------------------------------------------------
__global__ void zero_kernel(float* __restrict__ p, int n) {
    int i = blockIdx.x * 256 + threadIdx.x;
    if (i < n) p[i] = 0.0f;
}

__global__ void count_kernel(const int* __restrict__ batch, float* __restrict__ cnt, int N) {
    __shared__ int bins[NGRAPH];
    int t = threadIdx.x;
    if (t < NGRAPH) bins[t] = 0;
    __syncthreads();
    int i = blockIdx.x * 256 + t;
    if (i < N) atomicAdd(&bins[batch[i]], 1);
    __syncthreads();
    if (t < NGRAPH && bins[t] > 0) atomicAdd(&cnt[t], (float)bins[t]);
}

// ---------------------------------------------------------------------------
// effective-weight precompute:
//  Weff[path,b][a,bb,z] = scale * sum_{u,v,w} hl[a,u] ul[bb,v] w_path[u,v,w] lp[w,z]
//  path: 0=000, 1=110, 2=011, 3=101.  scale = 1/8192 (110: additionally /sqrt(3))
//  Stage A: tmp1[u,v,z] = scale * sum_w W[u,v,w] * L[w,z]
//  Stage B: tmp2[u,bb,z] = sum_v U[bb,v] * tmp1[u,v,z]
//  Stage C: Weff[a,bb,z] = sum_u H[a,u] * tmp2[u,bb,z]
// ---------------------------------------------------------------------------
__global__ void stageA_kernel(const float* __restrict__ w000, const float* __restrict__ w110,
                              const float* __restrict__ w011, const float* __restrict__ w101,
                              const float* __restrict__ lp0, const float* __restrict__ lp1,
                              float* __restrict__ tmp1) {
    int gid = blockIdx.x * 256 + threadIdx.x;
    int tslot = gid >> 15;            // b*4 + path
    int e = gid & 32767;
    int z = e & 31;
    int uv = e >> 5;
    int b = tslot >> 2, path = tslot & 3;
    const float* W = (path == 0 ? w000 : path == 1 ? w110 : path == 2 ? w011 : w101) + b * 32768;
    const float* L = ((path == 0 || path == 1) ? lp0 : lp1) + b * 1024;
    float scale = (path == 1) ? (1.0f / (8192.0f * 1.7320508075688772f)) : (1.0f / 8192.0f);
    const float* wr = W + uv * 32;
    float acc = 0.0f;
    for (int w = 0; w < 32; ++w) acc += wr[w] * L[w * 32 + z];
    tmp1[gid] = acc * scale;
}

__global__ void stageB_kernel(const float* __restrict__ ul0, const float* __restrict__ ul1,
                              const float* __restrict__ tmp1, float* __restrict__ tmp2) {
    int gid = blockIdx.x * 256 + threadIdx.x;
    int tslot = gid >> 15;
    int e = gid & 32767;
    int z = e & 31;
    int bb = (e >> 5) & 31;
    int u = e >> 10;
    int b = tslot >> 2, path = tslot & 3;
    const float* U = ((path == 0 || path == 3) ? ul0 : ul1) + b * 1024;  // su paths: 000,101
    const float* in = tmp1 + (size_t)tslot * 32768 + u * 1024 + z;
    float acc = 0.0f;
    for (int v = 0; v < 32; ++v) acc += U[bb * 32 + v] * in[v * 32];
    tmp2[gid] = acc;
}

__global__ void stageC_kernel(const float* __restrict__ hl0, const float* __restrict__ hl1,
                              const float* __restrict__ tmp2, float* __restrict__ Weff) {
    int gid = blockIdx.x * 256 + threadIdx.x;
    int tslot = gid >> 15;
    int e = gid & 32767;
    int z = e & 31;
    int bb = (e >> 5) & 31;
    int a = e >> 10;
    int b = tslot >> 2, path = tslot & 3;
    const float* H = ((path == 0 || path == 2) ? hl0 : hl1) + b * 1024;  // sh paths: 000,011
    const float* in = tmp2 + (size_t)tslot * 32768 + bb * 32 + z;
    float acc = 0.0f;
    for (int u = 0; u < 32; ++u) acc += H[a * 32 + u] * in[u * 1024];
    Weff[gid] = acc;
}

// ---------------------------------------------------------------------------
// main TP kernel helpers
// ---------------------------------------------------------------------------
template <bool FIRST>
__device__ __forceinline__ void tloop(const float* __restrict__ W, const float* __restrict__ X,
                                      int z, int bg, float (&T)[16][4]) {
#pragma unroll
    for (int n = 0; n < 16; ++n) { T[n][0] = 0.f; T[n][1] = 0.f; T[n][2] = 0.f; T[n][3] = 0.f; }
    const int b0 = bg * 4;
    for (int k = 0; k < 32; k += 2) {
        float w00, w01, w02, w03, w10, w11, w12, w13;
        if (FIRST) {
            const float* p0 = W + k * 1024 + b0 * 32 + z;
            w00 = p0[0];  w01 = p0[32];  w02 = p0[64];  w03 = p0[96];
            const float* p1 = p0 + 1024;
            w10 = p1[0];  w11 = p1[32];  w12 = p1[64];  w13 = p1[96];
        } else {
            const float* p0 = W + b0 * 1024 + k * 32 + z;
            w00 = p0[0];  w01 = p0[1024];  w02 = p0[2048];  w03 = p0[3072];
            const float* p1 = p0 + 32;
            w10 = p1[0];  w11 = p1[1024];  w12 = p1[2048];  w13 = p1[3072];
        }
#pragma unroll
        for (int n = 0; n < 16; ++n) {
            float2 s = *(const float2*)(X + n * 32 + k);
            T[n][0] += s.x * w00 + s.y * w10;
            T[n][1] += s.x * w01 + s.y * w11;
            T[n][2] += s.x * w02 + s.y * w12;
            T[n][3] += s.x * w03 + s.y * w13;
        }
    }
}

__device__ __forceinline__ void stage2_partial(float* __restrict__ red, const float* __restrict__ Y,
                                               const float (&T)[16][4], int z, int bg) {
    const int b0 = bg * 4;
#pragma unroll
    for (int n = 0; n < 16; ++n) {
        float p = Y[n * 32 + b0] * T[n][0] + Y[n * 32 + b0 + 1] * T[n][1]
                + Y[n * 32 + b0 + 2] * T[n][2] + Y[n * 32 + b0 + 3] * T[n][3];
        red[(bg * 16 + n) * 32 + z] = p;
    }
}

__device__ __forceinline__ void reduce_accum(float* __restrict__ red, float* __restrict__ zb,
                                             int t, int mode, float scale) {
    __syncthreads();
    for (int i = t; i < 512; i += 256) {
        int n = i >> 5, zz = i & 31;
        float s = red[(0 * 16 + n) * 32 + zz] + red[(1 * 16 + n) * 32 + zz]
                + red[(2 * 16 + n) * 32 + zz] + red[(3 * 16 + n) * 32 + zz]
                + red[(4 * 16 + n) * 32 + zz] + red[(5 * 16 + n) * 32 + zz]
                + red[(6 * 16 + n) * 32 + zz] + red[(7 * 16 + n) * 32 + zz];
        if (mode < 0) zb[n * 128 + zz] += s * scale;
        else          zb[n * 128 + 32 + zz * 3 + mode] += s * scale;
    }
    __syncthreads();
}

// ---------------------------------------------------------------------------
// TP + self-connection + stats kernel.  One WG per 16 nodes.
// thread = (z = t&31, bg = t>>5);  T[node][4 b-values] register tile.
// ---------------------------------------------------------------------------
__global__ __launch_bounds__(256, 2)
void tp_kernel(const float* __restrict__ hidden_b, const float* __restrict__ up,
               const float* __restrict__ Weff_b,
               const float* __restrict__ scw0, const float* __restrict__ scw1,
               const float* __restrict__ lp_b0,
               const int* __restrict__ species, const int* __restrict__ batch,
               float* __restrict__ S1, float* __restrict__ S2, float* __restrict__ V2,
               float* __restrict__ zout, int N) {
    __shared__ __align__(16) float sh_l[16][32];
    __shared__ __align__(16) float su_l[16][32];
    __shared__ __align__(16) float vh_l[3][16][32];   // c-major
    __shared__ __align__(16) float vu_l[3][16][32];
    __shared__ __align__(16) float red[8][16][32];
    __shared__ __align__(16) float zb[16][128];
    __shared__ int spec_l[16];
    __shared__ int bat_l[16];
    __shared__ float gs1[NGRAPH], gs2[NGRAPH], gv2[NGRAPH];

    const int t = threadIdx.x;
    const int z = t & 31;
    const int bg = t >> 5;
    const int n0 = blockIdx.x * NODE_TILE;
    const int nvalid = min(NODE_TILE, N - n0);

    float* redf = &red[0][0][0];
    float* zbf = &zb[0][0];

    // ---- load node tile ----
    for (int i = t; i < NODE_TILE * 128; i += 256) {
        int n = i >> 7, col = i & 127;
        float hv = 0.f, uv = 0.f;
        if (n < nvalid) {
            hv = hidden_b[(size_t)(n0 + n) * 128 + col];
            uv = up[(size_t)(n0 + n) * 128 + col];
        }
        if (col < 32) { sh_l[n][col] = hv; su_l[n][col] = uv; }
        else {
            int idx = col - 32;
            int c = idx % 3, u = idx / 3;
            vh_l[c][n][u] = hv; vu_l[c][n][u] = uv;
        }
    }
    if (t < NODE_TILE) {
        spec_l[t] = (t < nvalid) ? species[n0 + t] : 0;
        bat_l[t]  = (t < nvalid) ? batch[n0 + t] : 0;
    }
    for (int i = t; i < NODE_TILE * 128; i += 256) {
        int n = i >> 7, col = i & 127;
        zb[n][col] = (col < 32) ? lp_b0[col] : 0.f;
    }
    __syncthreads();

    const float* W000 = Weff_b;
    const float* W110 = Weff_b + 32768;
    const float* W011 = Weff_b + 2 * 32768;
    const float* W101 = Weff_b + 3 * 32768;

    float T[16][4];

    // ---- path 000: sh (x) su -> z0 ----
    tloop<true>(W000, &sh_l[0][0], z, bg, T);
    stage2_partial(redf, &su_l[0][0], T, z, bg);
    reduce_accum(redf, zbf, t, -1, 1.0f);

    // ---- path 011: sh (x) vu -> z1 ----
    tloop<true>(W011, &sh_l[0][0], z, bg, T);
    for (int c = 0; c < 3; ++c) {
        stage2_partial(redf, &vu_l[c][0][0], T, z, bg);
        reduce_accum(redf, zbf, t, c, 1.0f);
    }

    // ---- path 101: vh (x) su -> z1  (contract su into second index) ----
    tloop<false>(W101, &su_l[0][0], z, bg, T);
    for (int c = 0; c < 3; ++c) {
        stage2_partial(redf, &vh_l[c][0][0], T, z, bg);
        reduce_accum(redf, zbf, t, c, 1.0f);
    }

    // ---- path 110: vh . vu -> z0  (per c pass) ----
    for (int c = 0; c < 3; ++c) {
        tloop<true>(W110, &vh_l[c][0][0], z, bg, T);
        stage2_partial(redf, &vu_l[c][0][0], T, z, bg);
        reduce_accum(redf, zbf, t, -1, 1.0f);
    }

    // ---- self connection (scalar) ----
    {
        const int b0 = bg * 4;
#pragma unroll
        for (int n = 0; n < 16; ++n) {
            const float* w = scw0 + b0 * (NSPEC * 32) + spec_l[n] * 32 + z;
            float p = sh_l[n][b0] * w[0] + sh_l[n][b0 + 1] * w[320]
                    + sh_l[n][b0 + 2] * w[640] + sh_l[n][b0 + 3] * w[960];
            red[bg][n][z] = p;
        }
        reduce_accum(redf, zbf, t, -1, INV_SC);
    }
    // ---- self connection (vector) ----
    for (int c = 0; c < 3; ++c) {
        const int b0 = bg * 4;
#pragma unroll
        for (int n = 0; n < 16; ++n) {
            const float* w = scw1 + b0 * (NSPEC * 32) + spec_l[n] * 32 + z;
            float p = vh_l[c][n][b0] * w[0] + vh_l[c][n][b0 + 1] * w[320]
                    + vh_l[c][n][b0 + 2] * w[640] + vh_l[c][n][b0 + 3] * w[960];
            red[bg][n][z] = p;
        }
        reduce_accum(redf, zbf, t, c, INV_SC);
    }

    // ---- per-graph stats (sum s, sum s^2, sum |v|^2) ----
    if (t < NGRAPH) { gs1[t] = 0.f; gs2[t] = 0.f; gv2[t] = 0.f; }
    if (t < 64) {
        int n = t >> 2, q = t & 3;
        float s1 = 0.f, s2 = 0.f, v2 = 0.f;
#pragma unroll
        for (int k = 0; k < 8; ++k) { float x = zb[n][q * 8 + k]; s1 += x; s2 += x * x; }
#pragma unroll
        for (int k = 0; k < 24; ++k) { float x = zb[n][32 + q * 24 + k]; v2 += x * x; }
        red[q][n][0] = s1; red[q][n][1] = s2; red[q][n][2] = v2;
    }
    __syncthreads();
    if (t < NODE_TILE && t < nvalid) {
        float s1 = red[0][t][0] + red[1][t][0] + red[2][t][0] + red[3][t][0];
        float s2 = red[0][t][1] + red[1][t][1] + red[2][t][1] + red[3][t][1];
        float v2 = red[0][t][2] + red[1][t][2] + red[2][t][2] + red[3][t][2];
        int g = bat_l[t];
        atomicAdd(&gs1[g], s1); atomicAdd(&gs2[g], s2); atomicAdd(&gv2[g], v2);
    }
    __syncthreads();
    if (t < NGRAPH) {
        if (gs1[t] != 0.f) atomicAdd(&S1[t], gs1[t]);
        if (gs2[t] != 0.f) atomicAdd(&S2[t], gs2[t]);
        if (gv2[t] != 0.f) atomicAdd(&V2[t], gv2[t]);
    }

    // ---- store pre-norm z ----
    for (int i = t; i < nvalid * 128; i += 256)
        zout[(size_t)n0 * 128 + i] = zbf[i];
}

// ---------------------------------------------------------------------------
// LayerNorm + skip kernel (in-place on z written by tp_kernel)
// ---------------------------------------------------------------------------
__global__ __launch_bounds__(256)
void norm_kernel(const float* __restrict__ hidden_b, float* __restrict__ out_b,
                 const float* __restrict__ skw0, const float* __restrict__ skb0,
                 const float* __restrict__ skw1,
                 const float* __restrict__ lnw0, const float* __restrict__ lnb0,
                 const float* __restrict__ lnw1,
                 const int* __restrict__ batch,
                 const float* __restrict__ S1, const float* __restrict__ S2,
                 const float* __restrict__ V2, const float* __restrict__ cnt, int N) {
    __shared__ __align__(16) float sh_l[8][32];
    __shared__ __align__(16) float vh_l[8][96];
    const int t = threadIdx.x, z = t & 31, nl = t >> 5;
    const int n0 = blockIdx.x * 8;
    for (int i = t; i < 8 * 128; i += 256) {
        int n = i >> 7, col = i & 127;
        float v = (n0 + n < N) ? hidden_b[(size_t)(n0 + n) * 128 + col] : 0.f;
        if (col < 32) sh_l[n][col] = v; else vh_l[n][col - 32] = v;
    }
    __syncthreads();
    const int n = n0 + nl;
    if (n >= N) return;

    float sk0 = 0.f, s1 = 0.f, s2 = 0.f, s3 = 0.f;
    for (int a = 0; a < 32; ++a) {
        float w0 = skw0[a * 32 + z];
        float w1 = skw1[a * 32 + z];
        sk0 += sh_l[nl][a] * w0;
        s1 += vh_l[nl][a * 3 + 0] * w1;
        s2 += vh_l[nl][a * 3 + 1] * w1;
        s3 += vh_l[nl][a * 3 + 2] * w1;
    }
    int g = batch[n];
    float cM = fmaxf(cnt[g], 1.0f) * 32.0f;
    float mean = S1[g] / cM;
    float var = fmaxf(S2[g] / cM - mean * mean, 0.0f);
    float rs = rsqrtf(var + 1e-5f);
    float rv = rsqrtf(fmaxf(V2[g] / cM, 0.0f) + 1e-5f);

    size_t base = (size_t)n * 128;
    float z0 = out_b[base + z];
    out_b[base + z] = (z0 - mean) * rs * lnw0[z] + lnb0[z] + sk0 * INV32S + skb0[z];
    float lw = lnw1[z] * rv;
    float x0 = out_b[base + 32 + z * 3 + 0];
    float x1 = out_b[base + 32 + z * 3 + 1];
    float x2 = out_b[base + 32 + z * 3 + 2];
    out_b[base + 32 + z * 3 + 0] = x0 * lw + s1 * INV32S;
    out_b[base + 32 + z * 3 + 1] = x1 * lw + s2 * INV32S;
    out_b[base + 32 + z * 3 + 2] = x2 * lw + s3 * INV32S;
}

// ---------------------------------------------------------------------------
extern "C" void kernel_launch(void* const* d_in, const int* in_sizes, int n_in,
                              void* d_out, int out_size, void* d_ws, size_t ws_size,
                              hipStream_t stream) {
    const float* hidden = (const float*)d_in[0];
    const float* up0    = (const float*)d_in[1];
    const float* hl_w0  = (const float*)d_in[2];
    const float* hl_w1  = (const float*)d_in[3];
    const float* ul_w0  = (const float*)d_in[4];
    const float* ul_w1  = (const float*)d_in[5];
    const float* w000   = (const float*)d_in[6];
    const float* w110   = (const float*)d_in[7];
    const float* w011   = (const float*)d_in[8];
    const float* w101   = (const float*)d_in[9];
    const float* lp_w0  = (const float*)d_in[10];
    const float* lp_b0  = (const float*)d_in[11];
    const float* lp_w1  = (const float*)d_in[12];
    const float* sc_w0  = (const float*)d_in[13];
    const float* sc_w1  = (const float*)d_in[14];
    const float* ln_w0  = (const float*)d_in[15];
    const float* ln_b0  = (const float*)d_in[16];
    const float* ln_w1  = (const float*)d_in[17];
    const float* sk_w0  = (const float*)d_in[18];
    const float* sk_b0  = (const float*)d_in[19];
    const float* sk_w1  = (const float*)d_in[20];
    const int* species  = (const int*)d_in[21];
    const int* batch    = (const int*)d_in[22];
    float* out = (float*)d_out;

    const int N = in_sizes[21];
    const int B = in_sizes[0] / (N * 128);

    float* ws = (float*)d_ws;
    float* Weff = ws;                                  // B*4*32768
    float* tmp1 = Weff + (size_t)B * 4 * 32768;
    float* tmp2 = tmp1 + (size_t)B * 4 * 32768;
    float* stats = tmp2 + (size_t)B * 4 * 32768;       // cnt[16] + S1/S2/V2 [B*16] each
    float* cnt = stats;
    float* S1 = stats + NGRAPH;
    float* S2 = S1 + B * NGRAPH;
    float* V2 = S2 + B * NGRAPH;
    int statn = NGRAPH + 3 * B * NGRAPH;

    zero_kernel<<<1, 256, 0, stream>>>(stats, statn);
    count_kernel<<<(N + 255) / 256, 256, 0, stream>>>(batch, cnt, N);

    int nb = B * 4 * 32768 / 256;
    stageA_kernel<<<nb, 256, 0, stream>>>(w000, w110, w011, w101, lp_w0, lp_w1, tmp1);
    stageB_kernel<<<nb, 256, 0, stream>>>(ul_w0, ul_w1, tmp1, tmp2);
    stageC_kernel<<<nb, 256, 0, stream>>>(hl_w0, hl_w1, tmp2, Weff);

    for (int b = 0; b < B; ++b) {
        const float* up = (b == 0) ? up0 : out + (size_t)(b - 1) * N * 128;
        tp_kernel<<<(N + NODE_TILE - 1) / NODE_TILE, 256, 0, stream>>>(
            hidden + (size_t)b * N * 128, up, Weff + (size_t)b * 4 * 32768,
            sc_w0 + (size_t)b * MULT * NSPEC * MULT, sc_w1 + (size_t)b * MULT * NSPEC * MULT,
            lp_b0 + b * MULT, species, batch,
            S1 + b * NGRAPH, S2 + b * NGRAPH, V2 + b * NGRAPH,
            out + (size_t)b * N * 128, N);
        norm_kernel<<<(N + 7) / 8, 256, 0, stream>>>(
            hidden + (size_t)b * N * 128, out + (size_t)b * N * 128,
            sk_w0 + b * 1024, sk_b0 + b * MULT, sk_w1 + b * 1024,
            ln_w0 + b * MULT, ln_b0 + b * MULT, ln_w1 + b * MULT,
            batch, S1 + b * NGRAPH, S2 + b * NGRAPH, V2 + b * NGRAPH, cnt, N);
    }
}